// Round 2
// baseline (7210.183 us; speedup 1.0000x reference)
//
#include <hip/hip_runtime.h>
#include <math.h>

constexpr int Bn = 32, Sn = 512, Hn = 768, NHn = 12, DHn = 64, INTERn = 3072, En = 8;

// ---------------- routing ----------------

__global__ __launch_bounds__(256) void sent_kernel(const float* __restrict__ hid, float* __restrict__ c) {
  int b = blockIdx.x;
  int h = blockIdx.y * 256 + threadIdx.x;
  const float* p = hid + (size_t)b * Sn * Hn + h;
  float s = 0.f;
  for (int t = 0; t < Sn; t++) s += p[(size_t)t * Hn];
  c[b * Hn + h] = s * (1.f / (float)Sn);
}

__global__ __launch_bounds__(256) void center_kernel(float* __restrict__ c) {
  int h = blockIdx.x * 256 + threadIdx.x;
  float s = 0.f;
  for (int b = 0; b < Bn; b++) s += c[b * Hn + h];
  s *= (1.f / (float)Bn);
  for (int b = 0; b < Bn; b++) c[b * Hn + h] -= s;
}

// One block, 1024 threads: Gram 32x32, Jacobi eigensolve, keep-rule, k-means, write r[32].
__global__ __launch_bounds__(1024) void route_kernel(const float* __restrict__ c, int* __restrict__ r) {
  __shared__ float cl[32 * 772];          // padded stride 772 (16B-aligned rows)
  __shared__ float A[32][33];
  __shared__ float V[32][33];
  __shared__ float csA[32], snA[32];
  __shared__ int   partner[32], isP[32];
  __shared__ float Y[32][32];
  __shared__ float C[8][32];
  __shared__ float D[32][8];
  __shared__ int   asg[32], cnt[8];
  __shared__ float lam[32];
  __shared__ int   ord[32];
  __shared__ int   Psh;

  int tid = threadIdx.x;
  for (int g = tid; g < 32 * 768; g += 1024) {
    int i = g / 768; int hh = g - i * 768;
    cl[i * 772 + hh] = c[g];
  }
  __syncthreads();

  int i = tid >> 5, j = tid & 31;
  {
    const float* pi_ = cl + i * 772;
    const float* pj_ = cl + j * 772;
    float s = 0.f;
    for (int t = 0; t < 768; t += 4) {
      float4 x = *(const float4*)(pi_ + t);
      float4 y = *(const float4*)(pj_ + t);
      s += x.x * y.x + x.y * y.y + x.z * y.z + x.w * y.w;
    }
    A[i][j] = s;
    V[i][j] = (i == j) ? 1.f : 0.f;
  }
  __syncthreads();

  // parallel cyclic Jacobi, tournament schedule (16 disjoint pairs/round, 31 rounds/sweep)
  for (int sweep = 0; sweep < 10; sweep++) {
    for (int rnd = 0; rnd < 31; rnd++) {
      if (tid < 16) {
        int p, q;
        if (tid == 0) { p = rnd % 31; q = 31; }
        else { p = (rnd + tid) % 31; q = (rnd + 31 - tid) % 31; }
        float app = A[p][p], aqq = A[q][q], apq = A[p][q];
        float cc = 1.f, ss = 0.f;
        if (fabsf(apq) > 1e-18f) {
          float tau = (aqq - app) / (2.f * apq);
          float t = 1.f / (fabsf(tau) + sqrtf(1.f + tau * tau));
          if (tau < 0.f) t = -t;
          cc = 1.f / sqrtf(1.f + t * t);
          ss = t * cc;
        }
        partner[p] = q; partner[q] = p; isP[p] = 1; isP[q] = 0;
        csA[p] = cc; csA[q] = cc; snA[p] = ss; snA[q] = ss;
      }
      __syncthreads();
      {
        int pj = partner[j]; float cc = csA[j], ss = snA[j]; int ip = isP[j];
        float a = A[i][j], a2 = A[i][pj];
        float v1 = V[i][j], v2 = V[i][pj];
        float na = ip ? (cc * a - ss * a2) : (ss * a2 + cc * a);
        float nv = ip ? (cc * v1 - ss * v2) : (ss * v2 + cc * v1);
        __syncthreads();
        A[i][j] = na; V[i][j] = nv;
      }
      __syncthreads();
      {
        int pi2 = partner[i]; float cc = csA[i], ss = snA[i]; int ip = isP[i];
        float a = A[i][j], a2 = A[pi2][j];
        float na = ip ? (cc * a - ss * a2) : (ss * a2 + cc * a);
        __syncthreads();
        A[i][j] = na;
      }
      __syncthreads();
    }
  }

  if (tid < 32) { lam[tid] = A[tid][tid]; ord[tid] = tid; }
  __syncthreads();
  if (tid == 0) {
    for (int a = 0; a < 31; a++) {
      int mi = a;
      for (int b3 = a + 1; b3 < 32; b3++) if (lam[b3] > lam[mi]) mi = b3;
      float tl = lam[a]; lam[a] = lam[mi]; lam[mi] = tl;
      int to = ord[a]; ord[a] = ord[mi]; ord[mi] = to;
    }
    float tot = 0.f;
    for (int a = 0; a < 32; a++) tot += lam[a];
    float cum = 0.f; int P = 0;
    for (int a = 0; a < 32; a++) { float rate = lam[a] / tot; if (cum < 0.8f) P++; cum += rate; }
    Psh = P;
  }
  __syncthreads();
  Y[i][j] = (j < Psh) ? V[i][ord[j]] * sqrtf(fmaxf(lam[j], 0.f)) : 0.f;
  __syncthreads();
  if (tid < 256) { int jj = tid >> 5, kk = tid & 31; C[jj][kk] = Y[jj][kk]; }
  __syncthreads();

  for (int it = 0; it <= 20; it++) {
    if (tid < 256) {
      int ii = tid >> 3, jj = tid & 7;
      float s = 0.f;
      for (int kk = 0; kk < 32; kk++) { float d = Y[ii][kk] - C[jj][kk]; s += d * d; }
      D[ii][jj] = s;
    }
    __syncthreads();
    if (tid < 32) {
      int best = 0; float bd = D[tid][0];
      for (int jj = 1; jj < 8; jj++) if (D[tid][jj] < bd) { bd = D[tid][jj]; best = jj; }
      asg[tid] = best;
    }
    __syncthreads();
    if (it == 20) break;
    if (tid < 8) { int s = 0; for (int ii = 0; ii < 32; ii++) s += (asg[ii] == tid); cnt[tid] = s; }
    __syncthreads();
    if (tid < 256) {
      int jj = tid >> 5, kk = tid & 31;
      if (cnt[jj] > 0) {
        float s = 0.f;
        for (int ii = 0; ii < 32; ii++) if (asg[ii] == jj) s += Y[ii][kk];
        C[jj][kk] = s / (float)cnt[jj];
      }
    }
    __syncthreads();
  }
  if (tid < 32) r[tid] = asg[tid];
}

// ---------------- expert GEMM: Y = act(X @ W[e_b] + bias[e_b] (+ res)) ----------------
// X: per-batch M x K (row stride ldx, batch stride M*ldx, pre-offset by chunk);
// W: E x K x N; Y/res: per-batch M x N (pre-offset). r indexed at bofs+blockIdx.z.
template <int ACT>
__global__ __launch_bounds__(256) void gemm_expert(
    const float* __restrict__ X, const float* __restrict__ W,
    const float* __restrict__ bias, const float* __restrict__ res,
    float* __restrict__ Y, const int* __restrict__ r,
    int K, int N, int ldx, int bofs) {
  const int M = Sn;
  __shared__ float As[64][17];
  __shared__ float Bs[16][65];
  int b = blockIdx.z;
  int e = r[bofs + b];
  const float* Xb = X + (size_t)b * M * ldx + (size_t)blockIdx.y * 64 * ldx;
  const float* We = W + (size_t)e * K * N + blockIdx.x * 64;
  int tid = threadIdx.x;
  int ty = tid >> 4, tx = tid & 15;
  int arow = tid >> 2, acol = (tid & 3) * 4;
  int brow = tid >> 4, bcol = (tid & 15) * 4;
  float acc[4][4] = {};
  for (int k0 = 0; k0 < K; k0 += 16) {
    float4 av = *(const float4*)(Xb + (size_t)arow * ldx + k0 + acol);
    float4 bv = *(const float4*)(We + (size_t)(k0 + brow) * N + bcol);
    __syncthreads();
    As[arow][acol + 0] = av.x; As[arow][acol + 1] = av.y;
    As[arow][acol + 2] = av.z; As[arow][acol + 3] = av.w;
    Bs[brow][bcol + 0] = bv.x; Bs[brow][bcol + 1] = bv.y;
    Bs[brow][bcol + 2] = bv.z; Bs[brow][bcol + 3] = bv.w;
    __syncthreads();
#pragma unroll
    for (int kk = 0; kk < 16; kk++) {
      float a0 = As[ty * 4 + 0][kk], a1 = As[ty * 4 + 1][kk];
      float a2 = As[ty * 4 + 2][kk], a3 = As[ty * 4 + 3][kk];
      float b0 = Bs[kk][tx * 4 + 0], b1 = Bs[kk][tx * 4 + 1];
      float b2 = Bs[kk][tx * 4 + 2], b3 = Bs[kk][tx * 4 + 3];
      acc[0][0] += a0 * b0; acc[0][1] += a0 * b1; acc[0][2] += a0 * b2; acc[0][3] += a0 * b3;
      acc[1][0] += a1 * b0; acc[1][1] += a1 * b1; acc[1][2] += a1 * b2; acc[1][3] += a1 * b3;
      acc[2][0] += a2 * b0; acc[2][1] += a2 * b1; acc[2][2] += a2 * b2; acc[2][3] += a2 * b3;
      acc[3][0] += a3 * b0; acc[3][1] += a3 * b1; acc[3][2] += a3 * b2; acc[3][3] += a3 * b3;
    }
  }
  int row = blockIdx.y * 64 + ty * 4;
  int col = blockIdx.x * 64 + tx * 4;
#pragma unroll
  for (int i2 = 0; i2 < 4; i2++) {
    size_t off = ((size_t)b * M + row + i2) * N + col;
#pragma unroll
    for (int j2 = 0; j2 < 4; j2++) {
      float v = acc[i2][j2] + bias[e * N + col + j2];
      if (res) v += res[off + j2];
      if (ACT == 1) {
        float u = v;
        v = 0.5f * u * (1.f + tanhf(0.79788456080286535588f * (u + 0.044715f * u * u * u)));
      }
      Y[off + j2] = v;
    }
  }
}

// ---------------- attention: per (qtile, head, batch) ----------------
__global__ __launch_bounds__(256) void attn_kernel(const float* qbuf,
    const float* __restrict__ kbuf, const float* __restrict__ vbuf,
    const float* __restrict__ amask, float* ctx) {
  __shared__ float sc[32][520];
  __shared__ float qs[32][65];
  __shared__ float kv[64][65];
  int qt = blockIdx.x, h = blockIdx.y, b = blockIdx.z;
  int tid = threadIdx.x;
  int row0 = qt * 32;
  {
    int i = tid >> 3, dg = (tid & 7) * 8;
    const float* src = qbuf + ((size_t)(b * Sn + row0 + i) * Hn) + h * DHn + dg;
    float4 x0 = *(const float4*)src;
    float4 x1 = *(const float4*)(src + 4);
    qs[i][dg + 0] = x0.x; qs[i][dg + 1] = x0.y; qs[i][dg + 2] = x0.z; qs[i][dg + 3] = x0.w;
    qs[i][dg + 4] = x1.x; qs[i][dg + 5] = x1.y; qs[i][dg + 6] = x1.z; qs[i][dg + 7] = x1.w;
  }
  int qr = tid >> 3;
  int kg = (tid & 7) * 8;
  for (int kb0 = 0; kb0 < Sn; kb0 += 64) {
    __syncthreads();
    {
      int kk = tid >> 2, dg4 = (tid & 3) * 16;
      const float* src = kbuf + ((size_t)(b * Sn + kb0 + kk) * Hn) + h * DHn + dg4;
#pragma unroll
      for (int c4 = 0; c4 < 4; c4++) {
        float4 x = *(const float4*)(src + c4 * 4);
        kv[kk][dg4 + c4 * 4 + 0] = x.x; kv[kk][dg4 + c4 * 4 + 1] = x.y;
        kv[kk][dg4 + c4 * 4 + 2] = x.z; kv[kk][dg4 + c4 * 4 + 3] = x.w;
      }
    }
    __syncthreads();
    float acc[8] = {};
    for (int d = 0; d < 64; d++) {
      float qd = qs[qr][d];
#pragma unroll
      for (int j2 = 0; j2 < 8; j2++) acc[j2] += qd * kv[kg + j2][d];
    }
#pragma unroll
    for (int j2 = 0; j2 < 8; j2++) {
      int k = kb0 + kg + j2;
      sc[qr][k] = acc[j2] * 0.125f + (1.f - amask[b * Sn + k]) * (-10000.f);
    }
  }
  __syncthreads();
  // softmax: 4 waves x 8 rows
  int lane = tid & 63, wave = tid >> 6;
  for (int t = 0; t < 8; t++) {
    int rr = wave * 8 + t;
    float vals[8];
    float mx = -1e30f;
#pragma unroll
    for (int u = 0; u < 8; u++) { vals[u] = sc[rr][lane + 64 * u]; mx = fmaxf(mx, vals[u]); }
#pragma unroll
    for (int o = 32; o; o >>= 1) mx = fmaxf(mx, __shfl_xor(mx, o, 64));
    float sum = 0.f;
#pragma unroll
    for (int u = 0; u < 8; u++) { vals[u] = __expf(vals[u] - mx); sum += vals[u]; }
#pragma unroll
    for (int o = 32; o; o >>= 1) sum += __shfl_xor(sum, o, 64);
    float inv = 1.f / sum;
#pragma unroll
    for (int u = 0; u < 8; u++) sc[rr][lane + 64 * u] = vals[u] * inv;
  }
  // ctx = P @ V
  float acc2[8] = {};
  int dg = (tid & 7) * 8;
  for (int kb0 = 0; kb0 < Sn; kb0 += 64) {
    __syncthreads();
    {
      int kk = tid >> 2, dg4 = (tid & 3) * 16;
      const float* src = vbuf + ((size_t)(b * Sn + kb0 + kk) * Hn) + h * DHn + dg4;
#pragma unroll
      for (int c4 = 0; c4 < 4; c4++) {
        float4 x = *(const float4*)(src + c4 * 4);
        kv[kk][dg4 + c4 * 4 + 0] = x.x; kv[kk][dg4 + c4 * 4 + 1] = x.y;
        kv[kk][dg4 + c4 * 4 + 2] = x.z; kv[kk][dg4 + c4 * 4 + 3] = x.w;
      }
    }
    __syncthreads();
    for (int kk = 0; kk < 64; kk++) {
      float p = sc[qr][kb0 + kk];
#pragma unroll
      for (int j2 = 0; j2 < 8; j2++) acc2[j2] += p * kv[kk][dg + j2];
    }
  }
  __syncthreads();
  float* dst = ctx + ((size_t)(b * Sn + row0 + qr) * Hn) + h * DHn + dg;
  float4 o0 = make_float4(acc2[0], acc2[1], acc2[2], acc2[3]);
  float4 o1 = make_float4(acc2[4], acc2[5], acc2[6], acc2[7]);
  *(float4*)dst = o0;
  *(float4*)(dst + 4) = o1;
}

// ---------------- layernorm over H=768, per row ----------------
__global__ __launch_bounds__(256) void ln_kernel(const float* __restrict__ X, float* __restrict__ Y,
    const float* __restrict__ gam, const float* __restrict__ bet, const int* __restrict__ r) {
  __shared__ float red1[4], red2[4];
  int row = blockIdx.x;
  int tid = threadIdx.x;
  const float* x = X + (size_t)row * Hn;
  float v0 = x[tid], v1 = x[tid + 256], v2 = x[tid + 512];
  float s = v0 + v1 + v2;
#pragma unroll
  for (int o = 32; o; o >>= 1) s += __shfl_xor(s, o, 64);
  if ((tid & 63) == 0) red1[tid >> 6] = s;
  __syncthreads();
  float mu = (red1[0] + red1[1] + red1[2] + red1[3]) * (1.f / (float)Hn);
  float d0 = v0 - mu, d1 = v1 - mu, d2 = v2 - mu;
  float q = d0 * d0 + d1 * d1 + d2 * d2;
#pragma unroll
  for (int o = 32; o; o >>= 1) q += __shfl_xor(q, o, 64);
  if ((tid & 63) == 0) red2[tid >> 6] = q;
  __syncthreads();
  float var = (red2[0] + red2[1] + red2[2] + red2[3]) * (1.f / (float)Hn);
  float inv = rsqrtf(var + 1e-12f);
  int e = r[row >> 9];
  const float* g = gam + e * Hn;
  const float* be = bet + e * Hn;
  float* y = Y + (size_t)row * Hn;
  y[tid]       = d0 * inv * g[tid]       + be[tid];
  y[tid + 256] = d1 * inv * g[tid + 256] + be[tid + 256];
  y[tid + 512] = d2 * inv * g[tid + 512] + be[tid + 512];
}

// ---------------- launch ----------------
extern "C" void kernel_launch(void* const* d_in, const int* in_sizes, int n_in,
                              void* d_out, int out_size, void* d_ws, size_t ws_size,
                              hipStream_t stream) {
  const float* hidden = (const float*)d_in[0];
  const float* amask  = (const float*)d_in[1];
  const float* Wq = (const float*)d_in[2];
  const float* bq = (const float*)d_in[3];
  const float* Wk = (const float*)d_in[4];
  const float* bk = (const float*)d_in[5];
  const float* Wv = (const float*)d_in[6];
  const float* bv = (const float*)d_in[7];
  const float* Wo = (const float*)d_in[8];
  const float* bo = (const float*)d_in[9];
  const float* g1 = (const float*)d_in[10];
  const float* b1g = (const float*)d_in[11];
  const float* W1 = (const float*)d_in[12];
  const float* b1 = (const float*)d_in[13];
  const float* W2 = (const float*)d_in[14];
  const float* b2 = (const float*)d_in[15];
  const float* g2 = (const float*)d_in[16];
  const float* b2g = (const float*)d_in[17];
  float* out = (float*)d_out;

  char* w = (char*)d_ws;
  int* r = (int*)w;
  float* cbuf = (float*)(w + 1024);
  const size_t TOK = (size_t)Bn * Sn;               // 16384
  float* qb = (float*)(w + (1 << 20));
  float* kb = qb + TOK * Hn;                         // 12,582,912 floats each
  float* vb = kb + TOK * Hn;
  // total ws usage: 1 MiB + 3 * 48 MiB = 145 MiB (h1 chunks reuse kb)

  // routing
  sent_kernel<<<dim3(32, 3), 256, 0, stream>>>(hidden, cbuf);
  center_kernel<<<3, 256, 0, stream>>>(cbuf);
  route_kernel<<<1, 1024, 0, stream>>>(cbuf, r);

  // q, k, v projections
  gemm_expert<0><<<dim3(12, 8, 32), 256, 0, stream>>>(hidden, Wq, bq, nullptr, qb, r, Hn, Hn, Hn, 0);
  gemm_expert<0><<<dim3(12, 8, 32), 256, 0, stream>>>(hidden, Wk, bk, nullptr, kb, r, Hn, Hn, Hn, 0);
  gemm_expert<0><<<dim3(12, 8, 32), 256, 0, stream>>>(hidden, Wv, bv, nullptr, vb, r, Hn, Hn, Hn, 0);

  // attention (ctx written in-place over q regions per block; disjoint col ranges per head)
  attn_kernel<<<dim3(16, 12, 32), 256, 0, stream>>>(qb, kb, vb, amask, qb);

  // output projection + residual -> kb ; LN1 -> vb
  gemm_expert<0><<<dim3(12, 8, 32), 256, 0, stream>>>(qb, Wo, bo, hidden, kb, r, Hn, Hn, Hn, 0);
  ln_kernel<<<16384, 256, 0, stream>>>(kb, vb, g1, b1g, r);

  // FFN, chunked over batches (G=8) so h1 fits in kb's 48 MiB slot:
  // h1_chunk = gelu(att_chunk @ W1[e] + b1[e]) -> kb ; ffn_chunk -> qb (+ att residual)
  const int G = 8;
  for (int c = 0; c < Bn / G; c++) {
    const float* attc = vb + (size_t)c * G * Sn * Hn;
    float* h1c = kb;  // reused each chunk
    float* ffc = qb + (size_t)c * G * Sn * Hn;
    gemm_expert<1><<<dim3(48, 8, G), 256, 0, stream>>>(attc, W1, b1, nullptr, h1c, r, Hn, INTERn, Hn, c * G);
    gemm_expert<0><<<dim3(12, 8, G), 256, 0, stream>>>(h1c, W2, b2, attc, ffc, r, INTERn, Hn, INTERn, c * G);
  }
  ln_kernel<<<16384, 256, 0, stream>>>(qb, out, g2, b2g, r);
}

// Round 3
// 1624.218 us; speedup vs baseline: 4.4392x; 4.4392x over previous
//
#include <hip/hip_runtime.h>
#include <math.h>

constexpr int Bn = 32, Sn = 512, Hn = 768, NHn = 12, DHn = 64, INTERn = 3072, En = 8;

typedef __attribute__((ext_vector_type(4))) float f32x4;
typedef __attribute__((ext_vector_type(8))) short short8;
typedef __attribute__((ext_vector_type(4))) int int4v;

__device__ inline unsigned short f2b(float x) {
  unsigned u = __builtin_bit_cast(unsigned, x);
  return (unsigned short)((u + 0x7fffu + ((u >> 16) & 1u)) >> 16);
}
__device__ inline unsigned packpair(float a, float b) {
  return (unsigned)f2b(a) | ((unsigned)f2b(b) << 16);
}
__device__ inline short8 pack8(const float* p) {
  int4v w;
  w.x = (int)packpair(p[0], p[1]); w.y = (int)packpair(p[2], p[3]);
  w.z = (int)packpair(p[4], p[5]); w.w = (int)packpair(p[6], p[7]);
  return __builtin_bit_cast(short8, w);
}
__device__ inline float fast_gelu(float u) {
  float z = 0.7978845608028654f * (u + 0.044715f * u * u * u);
  float e = __expf(2.f * z);
  float t = 1.f - 2.f / (e + 1.f);
  return 0.5f * u * (1.f + t);
}

// ---------------- routing (unchanged, verified) ----------------

__global__ __launch_bounds__(256) void sent_kernel(const float* __restrict__ hid, float* __restrict__ c) {
  int b = blockIdx.x;
  int h = blockIdx.y * 256 + threadIdx.x;
  const float* p = hid + (size_t)b * Sn * Hn + h;
  float s = 0.f;
  for (int t = 0; t < Sn; t++) s += p[(size_t)t * Hn];
  c[b * Hn + h] = s * (1.f / (float)Sn);
}

__global__ __launch_bounds__(256) void center_kernel(float* __restrict__ c) {
  int h = blockIdx.x * 256 + threadIdx.x;
  float s = 0.f;
  for (int b = 0; b < Bn; b++) s += c[b * Hn + h];
  s *= (1.f / (float)Bn);
  for (int b = 0; b < Bn; b++) c[b * Hn + h] -= s;
}

__global__ __launch_bounds__(1024) void route_kernel(const float* __restrict__ c, int* __restrict__ r) {
  __shared__ float cl[32 * 772];
  __shared__ float A[32][33];
  __shared__ float V[32][33];
  __shared__ float csA[32], snA[32];
  __shared__ int   partner[32], isP[32];
  __shared__ float Y[32][32];
  __shared__ float C[8][32];
  __shared__ float D[32][8];
  __shared__ int   asg[32], cnt[8];
  __shared__ float lam[32];
  __shared__ int   ord[32];
  __shared__ int   Psh;

  int tid = threadIdx.x;
  for (int g = tid; g < 32 * 768; g += 1024) {
    int i = g / 768; int hh = g - i * 768;
    cl[i * 772 + hh] = c[g];
  }
  __syncthreads();

  int i = tid >> 5, j = tid & 31;
  {
    const float* pi_ = cl + i * 772;
    const float* pj_ = cl + j * 772;
    float s = 0.f;
    for (int t = 0; t < 768; t += 4) {
      float4 x = *(const float4*)(pi_ + t);
      float4 y = *(const float4*)(pj_ + t);
      s += x.x * y.x + x.y * y.y + x.z * y.z + x.w * y.w;
    }
    A[i][j] = s;
    V[i][j] = (i == j) ? 1.f : 0.f;
  }
  __syncthreads();

  for (int sweep = 0; sweep < 10; sweep++) {
    for (int rnd = 0; rnd < 31; rnd++) {
      if (tid < 16) {
        int p, q;
        if (tid == 0) { p = rnd % 31; q = 31; }
        else { p = (rnd + tid) % 31; q = (rnd + 31 - tid) % 31; }
        float app = A[p][p], aqq = A[q][q], apq = A[p][q];
        float cc = 1.f, ss = 0.f;
        if (fabsf(apq) > 1e-18f) {
          float tau = (aqq - app) / (2.f * apq);
          float t = 1.f / (fabsf(tau) + sqrtf(1.f + tau * tau));
          if (tau < 0.f) t = -t;
          cc = 1.f / sqrtf(1.f + t * t);
          ss = t * cc;
        }
        partner[p] = q; partner[q] = p; isP[p] = 1; isP[q] = 0;
        csA[p] = cc; csA[q] = cc; snA[p] = ss; snA[q] = ss;
      }
      __syncthreads();
      {
        int pj = partner[j]; float cc = csA[j], ss = snA[j]; int ip = isP[j];
        float a = A[i][j], a2 = A[i][pj];
        float v1 = V[i][j], v2 = V[i][pj];
        float na = ip ? (cc * a - ss * a2) : (ss * a2 + cc * a);
        float nv = ip ? (cc * v1 - ss * v2) : (ss * v2 + cc * v1);
        __syncthreads();
        A[i][j] = na; V[i][j] = nv;
      }
      __syncthreads();
      {
        int pi2 = partner[i]; float cc = csA[i], ss = snA[i]; int ip = isP[i];
        float a = A[i][j], a2 = A[pi2][j];
        float na = ip ? (cc * a - ss * a2) : (ss * a2 + cc * a);
        __syncthreads();
        A[i][j] = na;
      }
      __syncthreads();
    }
  }

  if (tid < 32) { lam[tid] = A[tid][tid]; ord[tid] = tid; }
  __syncthreads();
  if (tid == 0) {
    for (int a = 0; a < 31; a++) {
      int mi = a;
      for (int b3 = a + 1; b3 < 32; b3++) if (lam[b3] > lam[mi]) mi = b3;
      float tl = lam[a]; lam[a] = lam[mi]; lam[mi] = tl;
      int to = ord[a]; ord[a] = ord[mi]; ord[mi] = to;
    }
    float tot = 0.f;
    for (int a = 0; a < 32; a++) tot += lam[a];
    float cum = 0.f; int P = 0;
    for (int a = 0; a < 32; a++) { float rate = lam[a] / tot; if (cum < 0.8f) P++; cum += rate; }
    Psh = P;
  }
  __syncthreads();
  Y[i][j] = (j < Psh) ? V[i][ord[j]] * sqrtf(fmaxf(lam[j], 0.f)) : 0.f;
  __syncthreads();
  if (tid < 256) { int jj = tid >> 5, kk = tid & 31; C[jj][kk] = Y[jj][kk]; }
  __syncthreads();

  for (int it = 0; it <= 20; it++) {
    if (tid < 256) {
      int ii = tid >> 3, jj = tid & 7;
      float s = 0.f;
      for (int kk = 0; kk < 32; kk++) { float d = Y[ii][kk] - C[jj][kk]; s += d * d; }
      D[ii][jj] = s;
    }
    __syncthreads();
    if (tid < 32) {
      int best = 0; float bd = D[tid][0];
      for (int jj = 1; jj < 8; jj++) if (D[tid][jj] < bd) { bd = D[tid][jj]; best = jj; }
      asg[tid] = best;
    }
    __syncthreads();
    if (it == 20) break;
    if (tid < 8) { int s = 0; for (int ii = 0; ii < 32; ii++) s += (asg[ii] == tid); cnt[tid] = s; }
    __syncthreads();
    if (tid < 256) {
      int jj = tid >> 5, kk = tid & 31;
      if (cnt[jj] > 0) {
        float s = 0.f;
        for (int ii = 0; ii < 32; ii++) if (asg[ii] == jj) s += Y[ii][kk];
        C[jj][kk] = s / (float)cnt[jj];
      }
    }
    __syncthreads();
  }
  if (tid < 32) r[tid] = asg[tid];
}

// ---------------- bf16 MFMA expert GEMM ----------------
// Y[b] = act(X[b] @ W[r[bofs+b]] + bias (+ res)).  X f32 (M=512 x K, row stride ldx),
// W f32 (E x K x N).  Tile 128x128, BK=32, 4 waves of 64x64.  f32->bf16 on the fly.
template <int ACT, int HASRES>
__global__ __launch_bounds__(256) void gemm_bf16(
    const float* __restrict__ X, const float* __restrict__ W,
    const float* __restrict__ bias, const float* __restrict__ res,
    float* __restrict__ Y, const int* __restrict__ r,
    int K, int N, int ldx, int bofs) {
  __shared__ short As[2][128][40];   // [row][k] bf16, pad to 40
  __shared__ short Bt[2][128][40];   // [col][k] bf16 (B transposed)
  int b = blockIdx.z;
  int e = r[bofs + b];
  const float* Xb = X + (size_t)b * Sn * ldx + (size_t)blockIdx.y * 128 * ldx;
  const float* We = W + (size_t)e * K * N + blockIdx.x * 128;
  int tid = threadIdx.x;
  int sar = tid >> 1, sac = (tid & 1) * 16;   // A: row, 16-float k-chunk
  int sbc = tid >> 1, sbk = (tid & 1) * 16;   // B: col n, 16-float k-chunk
  int wid = tid >> 6, lane = tid & 63;
  int wy = wid >> 1, wx = wid & 1;
  int lr = lane & 15, lg = lane >> 4;

  float av[16], bv[16];
  int nk = K / 32;

  // prologue: tile 0
  {
    const float* ap = Xb + (size_t)sar * ldx + sac;
#pragma unroll
    for (int c = 0; c < 4; c++) {
      float4 x = *(const float4*)(ap + c * 4);
      av[c * 4 + 0] = x.x; av[c * 4 + 1] = x.y; av[c * 4 + 2] = x.z; av[c * 4 + 3] = x.w;
    }
    const float* bp = We + (size_t)sbk * N + sbc;
#pragma unroll
    for (int i2 = 0; i2 < 16; i2++) bv[i2] = bp[(size_t)i2 * N];
    *(short8*)&As[0][sar][sac] = pack8(&av[0]);
    *(short8*)&As[0][sar][sac + 8] = pack8(&av[8]);
    *(short8*)&Bt[0][sbc][sbk] = pack8(&bv[0]);
    *(short8*)&Bt[0][sbc][sbk + 8] = pack8(&bv[8]);
  }
  __syncthreads();

  f32x4 acc[4][4];
#pragma unroll
  for (int m = 0; m < 4; m++)
#pragma unroll
    for (int n = 0; n < 4; n++) acc[m][n] = (f32x4){0.f, 0.f, 0.f, 0.f};

  for (int ks = 0; ks < nk; ks++) {
    int cur = ks & 1;
    if (ks + 1 < nk) {
      int k0 = (ks + 1) * 32;
      const float* ap = Xb + (size_t)sar * ldx + k0 + sac;
#pragma unroll
      for (int c = 0; c < 4; c++) {
        float4 x = *(const float4*)(ap + c * 4);
        av[c * 4 + 0] = x.x; av[c * 4 + 1] = x.y; av[c * 4 + 2] = x.z; av[c * 4 + 3] = x.w;
      }
      const float* bp = We + (size_t)(k0 + sbk) * N + sbc;
#pragma unroll
      for (int i2 = 0; i2 < 16; i2++) bv[i2] = bp[(size_t)i2 * N];
    }
    // compute current tile
    short8 af[4], bf[4];
#pragma unroll
    for (int m = 0; m < 4; m++) af[m] = *(short8*)&As[cur][wy * 64 + m * 16 + lr][lg * 8];
#pragma unroll
    for (int n = 0; n < 4; n++) bf[n] = *(short8*)&Bt[cur][wx * 64 + n * 16 + lr][lg * 8];
#pragma unroll
    for (int m = 0; m < 4; m++)
#pragma unroll
      for (int n = 0; n < 4; n++)
        acc[m][n] = __builtin_amdgcn_mfma_f32_16x16x32_bf16(af[m], bf[n], acc[m][n], 0, 0, 0);
    if (ks + 1 < nk) {
      int nb = cur ^ 1;
      *(short8*)&As[nb][sar][sac] = pack8(&av[0]);
      *(short8*)&As[nb][sar][sac + 8] = pack8(&av[8]);
      *(short8*)&Bt[nb][sbc][sbk] = pack8(&bv[0]);
      *(short8*)&Bt[nb][sbc][sbk + 8] = pack8(&bv[8]);
    }
    __syncthreads();
  }

  // epilogue: C row = (lg*4+r), col = lr within each 16x16 fragment
  int row0 = blockIdx.y * 128 + wy * 64;
  int col0 = blockIdx.x * 128 + wx * 64;
#pragma unroll
  for (int m = 0; m < 4; m++) {
#pragma unroll
    for (int n = 0; n < 4; n++) {
      int col = col0 + n * 16 + lr;
      float bias_v = bias[e * N + col];
#pragma unroll
      for (int rr = 0; rr < 4; rr++) {
        int row = row0 + m * 16 + lg * 4 + rr;
        size_t off = ((size_t)b * Sn + row) * N + col;
        float v = acc[m][n][rr] + bias_v;
        if (HASRES) v += res[off];
        if (ACT == 1) v = fast_gelu(v);
        Y[off] = v;
      }
    }
  }
}

// ---------------- MFMA flash attention ----------------
// Block = (qtile of 64, head, batch); 4 waves x 16 q-rows. Swapped QK^T (S^T = K Q^T)
// so each lane owns scores of one q-row; online softmax; PV accumulates O^T.
__global__ __launch_bounds__(256) void attn_mfma(
    const float* __restrict__ qb, const float* __restrict__ kb,
    const float* __restrict__ vb, const float* __restrict__ amask,
    float* __restrict__ ctx) {
  __shared__ short Kl[32][72];   // [kv][d] bf16, pad 64->72
  __shared__ short Vt[64][40];   // [d][kv] bf16, pad 32->40
  __shared__ float mk[512];
  int qt = blockIdx.x, h = blockIdx.y, b = blockIdx.z;
  int tid = threadIdx.x, w = tid >> 6, lane = tid & 63;
  int lr = lane & 15, lg = lane >> 4;

  for (int i2 = tid; i2 < 512; i2 += 256) mk[i2] = (1.f - amask[b * Sn + i2]) * (-10000.f);

  // Q fragments (Q^T B-frags): lane holds Q[qrow][d-chunk]
  int qrow = qt * 64 + w * 16 + lr;
  const float* qp = qb + ((size_t)(b * Sn + qrow)) * Hn + h * 64 + lg * 8;
  short8 qf0, qf1;
  {
    float t0[8], t1[8];
#pragma unroll
    for (int i2 = 0; i2 < 8; i2++) t0[i2] = qp[i2];
#pragma unroll
    for (int i2 = 0; i2 < 8; i2++) t1[i2] = qp[32 + i2];
    qf0 = pack8(t0); qf1 = pack8(t1);
  }

  f32x4 o[4];
#pragma unroll
  for (int f = 0; f < 4; f++) o[f] = (f32x4){0.f, 0.f, 0.f, 0.f};
  float mrun = -3e38f, lsum = 0.f;

  for (int kv0 = 0; kv0 < Sn; kv0 += 32) {
    __syncthreads();
    {  // stage K tile [32][64]
      int kvr = tid >> 3, i8 = tid & 7;
      const float* kp = kb + ((size_t)(b * Sn + kv0 + kvr)) * Hn + h * 64 + i8 * 8;
      float t[8];
#pragma unroll
      for (int i2 = 0; i2 < 8; i2++) t[i2] = kp[i2];
      *(short8*)&Kl[kvr][i8 * 8] = pack8(t);
    }
    {  // stage V^T tile [64 d][32 kv]
      int d = tid & 63, kq = tid >> 6;
      const float* vp = vb + ((size_t)(b * Sn + kv0 + kq * 8)) * Hn + h * 64 + d;
      float t[8];
#pragma unroll
      for (int i2 = 0; i2 < 8; i2++) t[i2] = vp[(size_t)i2 * Hn];
      *(short8*)&Vt[d][kq * 8] = pack8(t);
    }
    __syncthreads();

    // S^T fragments: s0 = kv 0..15, s1 = kv 16..31 (cols = q)
    f32x4 s0 = (f32x4){0.f, 0.f, 0.f, 0.f}, s1 = s0;
    short8 k00 = *(short8*)&Kl[lr][lg * 8];
    short8 k01 = *(short8*)&Kl[lr][32 + lg * 8];
    short8 k10 = *(short8*)&Kl[16 + lr][lg * 8];
    short8 k11 = *(short8*)&Kl[16 + lr][32 + lg * 8];
    s0 = __builtin_amdgcn_mfma_f32_16x16x32_bf16(k00, qf0, s0, 0, 0, 0);
    s0 = __builtin_amdgcn_mfma_f32_16x16x32_bf16(k01, qf1, s0, 0, 0, 0);
    s1 = __builtin_amdgcn_mfma_f32_16x16x32_bf16(k10, qf0, s1, 0, 0, 0);
    s1 = __builtin_amdgcn_mfma_f32_16x16x32_bf16(k11, qf1, s1, 0, 0, 0);

    f32x4 m0 = *(f32x4*)&mk[kv0 + lg * 4];
    f32x4 m1 = *(f32x4*)&mk[kv0 + 16 + lg * 4];
#pragma unroll
    for (int rr = 0; rr < 4; rr++) { s0[rr] = s0[rr] * 0.125f + m0[rr]; s1[rr] = s1[rr] * 0.125f + m1[rr]; }

    float pm = fmaxf(fmaxf(fmaxf(s0[0], s0[1]), fmaxf(s0[2], s0[3])),
                     fmaxf(fmaxf(s1[0], s1[1]), fmaxf(s1[2], s1[3])));
    pm = fmaxf(pm, __shfl_xor(pm, 16, 64));
    pm = fmaxf(pm, __shfl_xor(pm, 32, 64));
    float mn = fmaxf(mrun, pm);
    float al = __expf(mrun - mn);
    float p0[4], p1[4];
    float ls = 0.f;
#pragma unroll
    for (int rr = 0; rr < 4; rr++) { p0[rr] = __expf(s0[rr] - mn); ls += p0[rr]; }
#pragma unroll
    for (int rr = 0; rr < 4; rr++) { p1[rr] = __expf(s1[rr] - mn); ls += p1[rr]; }
    ls += __shfl_xor(ls, 16, 64);
    ls += __shfl_xor(ls, 32, 64);
    lsum = lsum * al + ls;
    mrun = mn;
#pragma unroll
    for (int f = 0; f < 4; f++)
#pragma unroll
      for (int rr = 0; rr < 4; rr++) o[f][rr] *= al;

    // build P^T B-frag: lane needs P^T[kv = lg*8 + jj][q=lr]
    unsigned a0p = packpair(p0[0], p0[1]), a1p = packpair(p0[2], p0[3]);
    unsigned b0p = packpair(p1[0], p1[1]), b1p = packpair(p1[2], p1[3]);
    int srcA = lr + (((2 * lg) & 3) << 4);
    int srcB = srcA + 16;
    unsigned xa0 = __shfl(a0p, srcA, 64), xa1 = __shfl(a1p, srcA, 64);
    unsigned xb0 = __shfl(b0p, srcA, 64), xb1 = __shfl(b1p, srcA, 64);
    unsigned ya0 = __shfl(a0p, srcB, 64), ya1 = __shfl(a1p, srcB, 64);
    unsigned yb0 = __shfl(b0p, srcB, 64), yb1 = __shfl(b1p, srcB, 64);
    bool lo = lg < 2;
    int4v pw;
    pw.x = (int)(lo ? xa0 : xb0); pw.y = (int)(lo ? xa1 : xb1);
    pw.z = (int)(lo ? ya0 : yb0); pw.w = (int)(lo ? ya1 : yb1);
    short8 pf = __builtin_bit_cast(short8, pw);

#pragma unroll
    for (int f = 0; f < 4; f++) {
      short8 vf = *(short8*)&Vt[f * 16 + lr][lg * 8];
      o[f] = __builtin_amdgcn_mfma_f32_16x16x32_bf16(vf, pf, o[f], 0, 0, 0);
    }
  }

  float inv = 1.f / lsum;
  float* op = ctx + ((size_t)(b * Sn + qt * 64 + w * 16 + lr)) * Hn + h * 64;
#pragma unroll
  for (int f = 0; f < 4; f++) {
    float4 vv = make_float4(o[f][0] * inv, o[f][1] * inv, o[f][2] * inv, o[f][3] * inv);
    *(float4*)(op + f * 16 + lg * 4) = vv;
  }
}

// ---------------- layernorm ----------------
__global__ __launch_bounds__(256) void ln_kernel(const float* __restrict__ X, float* __restrict__ Y,
    const float* __restrict__ gam, const float* __restrict__ bet, const int* __restrict__ r) {
  __shared__ float red1[4], red2[4];
  int row = blockIdx.x;
  int tid = threadIdx.x;
  const float* x = X + (size_t)row * Hn;
  float v0 = x[tid], v1 = x[tid + 256], v2 = x[tid + 512];
  float s = v0 + v1 + v2;
#pragma unroll
  for (int o = 32; o; o >>= 1) s += __shfl_xor(s, o, 64);
  if ((tid & 63) == 0) red1[tid >> 6] = s;
  __syncthreads();
  float mu = (red1[0] + red1[1] + red1[2] + red1[3]) * (1.f / (float)Hn);
  float d0 = v0 - mu, d1 = v1 - mu, d2 = v2 - mu;
  float q = d0 * d0 + d1 * d1 + d2 * d2;
#pragma unroll
  for (int o = 32; o; o >>= 1) q += __shfl_xor(q, o, 64);
  if ((tid & 63) == 0) red2[tid >> 6] = q;
  __syncthreads();
  float var = (red2[0] + red2[1] + red2[2] + red2[3]) * (1.f / (float)Hn);
  float inv = rsqrtf(var + 1e-12f);
  int e = r[row >> 9];
  const float* g = gam + e * Hn;
  const float* be = bet + e * Hn;
  float* y = Y + (size_t)row * Hn;
  y[tid]       = d0 * inv * g[tid]       + be[tid];
  y[tid + 256] = d1 * inv * g[tid + 256] + be[tid + 256];
  y[tid + 512] = d2 * inv * g[tid + 512] + be[tid + 512];
}

// ---------------- launch ----------------
extern "C" void kernel_launch(void* const* d_in, const int* in_sizes, int n_in,
                              void* d_out, int out_size, void* d_ws, size_t ws_size,
                              hipStream_t stream) {
  const float* hidden = (const float*)d_in[0];
  const float* amask  = (const float*)d_in[1];
  const float* Wq = (const float*)d_in[2];
  const float* bq = (const float*)d_in[3];
  const float* Wk = (const float*)d_in[4];
  const float* bk = (const float*)d_in[5];
  const float* Wv = (const float*)d_in[6];
  const float* bv = (const float*)d_in[7];
  const float* Wo = (const float*)d_in[8];
  const float* bo = (const float*)d_in[9];
  const float* g1 = (const float*)d_in[10];
  const float* b1g = (const float*)d_in[11];
  const float* W1 = (const float*)d_in[12];
  const float* b1 = (const float*)d_in[13];
  const float* W2 = (const float*)d_in[14];
  const float* b2 = (const float*)d_in[15];
  const float* g2 = (const float*)d_in[16];
  const float* b2g = (const float*)d_in[17];
  float* out = (float*)d_out;

  char* w = (char*)d_ws;
  int* r = (int*)w;
  float* cbuf = (float*)(w + 1024);
  const size_t TOK = (size_t)Bn * Sn;               // 16384
  float* qb = (float*)(w + (1 << 20));
  float* kb = qb + TOK * Hn;
  float* vb = kb + TOK * Hn;
  // ws usage: 1 MiB + 3 * 48 MiB = 145 MiB (FFN h1 chunks reuse kb: 8*512*3072*4 == 16384*768*4)

  // routing
  sent_kernel<<<dim3(32, 3), 256, 0, stream>>>(hidden, cbuf);
  center_kernel<<<3, 256, 0, stream>>>(cbuf);
  route_kernel<<<1, 1024, 0, stream>>>(cbuf, r);

  // q, k, v projections
  gemm_bf16<0, 0><<<dim3(6, 4, 32), 256, 0, stream>>>(hidden, Wq, bq, nullptr, qb, r, Hn, Hn, Hn, 0);
  gemm_bf16<0, 0><<<dim3(6, 4, 32), 256, 0, stream>>>(hidden, Wk, bk, nullptr, kb, r, Hn, Hn, Hn, 0);
  gemm_bf16<0, 0><<<dim3(6, 4, 32), 256, 0, stream>>>(hidden, Wv, bv, nullptr, vb, r, Hn, Hn, Hn, 0);

  // attention: ctx overwrites qb in place (each block reads/writes only its own q-region)
  attn_mfma<<<dim3(8, 12, 32), 256, 0, stream>>>(qb, kb, vb, amask, qb);

  // output projection + residual -> kb ; LN1 -> vb
  gemm_bf16<0, 1><<<dim3(6, 4, 32), 256, 0, stream>>>(qb, Wo, bo, hidden, kb, r, Hn, Hn, Hn, 0);
  ln_kernel<<<16384, 256, 0, stream>>>(kb, vb, g1, b1g, r);

  // FFN, chunked over batches (G=8): h1 chunk lives in kb
  const int G = 8;
  for (int c = 0; c < Bn / G; c++) {
    const float* attc = vb + (size_t)c * G * Sn * Hn;
    float* h1c = kb;
    float* ffc = qb + (size_t)c * G * Sn * Hn;
    gemm_bf16<1, 0><<<dim3(24, 4, G), 256, 0, stream>>>(attc, W1, b1, nullptr, h1c, r, Hn, INTERn, Hn, c * G);
    gemm_bf16<0, 1><<<dim3(6, 4, G), 256, 0, stream>>>(h1c, W2, b2, attc, ffc, r, INTERn, Hn, INTERn, c * G);
  }
  ln_kernel<<<16384, 256, 0, stream>>>(qb, out, g2, b2g, r);
}

// Round 4
// 1087.801 us; speedup vs baseline: 6.6282x; 1.4931x over previous
//
#include <hip/hip_runtime.h>
#include <math.h>

constexpr int Bn = 32, Sn = 512, Hn = 768, NHn = 12, DHn = 64, INTERn = 3072, En = 8;

typedef __attribute__((ext_vector_type(4))) float f32x4;
typedef __attribute__((ext_vector_type(8))) short short8;
typedef __attribute__((ext_vector_type(4))) int int4v;

__device__ inline unsigned short f2b(float x) {
  unsigned u = __builtin_bit_cast(unsigned, x);
  return (unsigned short)((u + 0x7fffu + ((u >> 16) & 1u)) >> 16);
}
__device__ inline float b2f(unsigned short u) {
  unsigned x = ((unsigned)u) << 16;
  return __builtin_bit_cast(float, x);
}
__device__ inline unsigned packpair(float a, float b) {
  return (unsigned)f2b(a) | ((unsigned)f2b(b) << 16);
}
__device__ inline short8 pack8(const float* p) {
  int4v w;
  w.x = (int)packpair(p[0], p[1]); w.y = (int)packpair(p[2], p[3]);
  w.z = (int)packpair(p[4], p[5]); w.w = (int)packpair(p[6], p[7]);
  return __builtin_bit_cast(short8, w);
}
__device__ inline float fast_gelu(float u) {
  float z = 0.7978845608028654f * (u + 0.044715f * u * u * u);
  float e = __expf(2.f * z);
  float t = 1.f - 2.f / (e + 1.f);
  return 0.5f * u * (1.f + t);
}
// async global->LDS, 16B per lane; lds base must be wave-uniform (HW adds lane*16)
__device__ inline void gload16(const void* g, void* l) {
  __builtin_amdgcn_global_load_lds(
      (const __attribute__((address_space(1))) unsigned int*)g,
      (__attribute__((address_space(3))) unsigned int*)l, 16, 0, 0);
}

// ---------------- routing ----------------

__global__ __launch_bounds__(256) void sent_kernel(const float* __restrict__ hid, float* __restrict__ c) {
  int b = blockIdx.x;
  int h = blockIdx.y * 256 + threadIdx.x;
  const float* p = hid + (size_t)b * Sn * Hn + h;
  float s = 0.f;
  for (int t = 0; t < Sn; t++) s += p[(size_t)t * Hn];
  c[b * Hn + h] = s * (1.f / (float)Sn);
}

__global__ __launch_bounds__(256) void center_kernel(float* __restrict__ c) {
  int h = blockIdx.x * 256 + threadIdx.x;
  float s = 0.f;
  for (int b = 0; b < Bn; b++) s += c[b * Hn + h];
  s *= (1.f / (float)Bn);
  for (int b = 0; b < Bn; b++) c[b * Hn + h] -= s;
}

// Gram 32x32 of centered sentence embeddings -> gA (f32[1024])
__global__ __launch_bounds__(1024) void gram_kernel(const float* __restrict__ c, float* __restrict__ gA) {
  __shared__ float cl[32 * 772];
  int tid = threadIdx.x;
  for (int g = tid; g < 32 * 768; g += 1024) {
    int i = g / 768; int hh = g - i * 768;
    cl[i * 772 + hh] = c[g];
  }
  __syncthreads();
  int i = tid >> 5, j = tid & 31;
  const float* pi_ = cl + i * 772;
  const float* pj_ = cl + j * 772;
  float s = 0.f;
  for (int t = 0; t < 768; t += 4) {
    float4 x = *(const float4*)(pi_ + t);
    float4 y = *(const float4*)(pj_ + t);
    s += x.x * y.x + x.y * y.y + x.z * y.z + x.w * y.w;
  }
  gA[i * 32 + j] = s;
}

// 256 threads: Jacobi eigensolve (early-exit on convergence), keep-rule, k-means.
__global__ __launch_bounds__(256) void route_kernel(const float* __restrict__ gA, int* __restrict__ r) {
  __shared__ float A[32][33];
  __shared__ float V[32][33];
  __shared__ float csA[32], snA[32];
  __shared__ int   partner[32], isP[32];
  __shared__ float Y[32][32];
  __shared__ float C[8][32];
  __shared__ float D[32][8];
  __shared__ int   asg[32], cnt[8];
  __shared__ float lam[32];
  __shared__ int   ord[32];
  __shared__ int   Psh;
  __shared__ int   done;
  __shared__ float tolS;
  __shared__ float wred[4];

  int tid = threadIdx.x;
  int i0 = tid >> 5, j = tid & 31;   // rows i0+8e, e=0..3
#pragma unroll
  for (int e = 0; e < 4; e++) {
    int i = i0 + 8 * e;
    A[i][j] = gA[i * 32 + j];
    V[i][j] = (i == j) ? 1.f : 0.f;
  }
  if (tid == 0) {
    float t2 = 0.f;
    for (int a = 0; a < 32; a++) { float d = gA[a * 32 + a]; t2 += d * d; }
    tolS = 1e-10f * t2 + 1e-30f;
    done = 0;
  }
  __syncthreads();

  for (int sweep = 0; sweep < 10; sweep++) {
    for (int rnd = 0; rnd < 31; rnd++) {
      if (tid < 16) {
        int p, q;
        if (tid == 0) { p = rnd % 31; q = 31; }
        else { p = (rnd + tid) % 31; q = (rnd + 31 - tid) % 31; }
        float app = A[p][p], aqq = A[q][q], apq = A[p][q];
        float cc = 1.f, ss = 0.f;
        if (fabsf(apq) > 1e-18f) {
          float tau = (aqq - app) / (2.f * apq);
          float t = 1.f / (fabsf(tau) + sqrtf(1.f + tau * tau));
          if (tau < 0.f) t = -t;
          cc = 1.f / sqrtf(1.f + t * t);
          ss = t * cc;
        }
        partner[p] = q; partner[q] = p; isP[p] = 1; isP[q] = 0;
        csA[p] = cc; csA[q] = cc; snA[p] = ss; snA[q] = ss;
      }
      __syncthreads();
      float na[4], nv[4], nb[4];
      {
        int pj = partner[j]; float cc = csA[j], ss = snA[j]; int ip = isP[j];
#pragma unroll
        for (int e = 0; e < 4; e++) {
          int i = i0 + 8 * e;
          float a = A[i][j], a2 = A[i][pj];
          float v1 = V[i][j], v2 = V[i][pj];
          na[e] = ip ? (cc * a - ss * a2) : (ss * a2 + cc * a);
          nv[e] = ip ? (cc * v1 - ss * v2) : (ss * v2 + cc * v1);
        }
      }
      __syncthreads();
#pragma unroll
      for (int e = 0; e < 4; e++) { int i = i0 + 8 * e; A[i][j] = na[e]; V[i][j] = nv[e]; }
      __syncthreads();
#pragma unroll
      for (int e = 0; e < 4; e++) {
        int i = i0 + 8 * e;
        int pi2 = partner[i]; float cc = csA[i], ss = snA[i]; int ip = isP[i];
        float a = A[i][j], a2 = A[pi2][j];
        nb[e] = ip ? (cc * a - ss * a2) : (ss * a2 + cc * a);
      }
      __syncthreads();
#pragma unroll
      for (int e = 0; e < 4; e++) { int i = i0 + 8 * e; A[i][j] = nb[e]; }
      __syncthreads();
    }
    // convergence check
    float off2 = 0.f;
#pragma unroll
    for (int e = 0; e < 4; e++) {
      int i = i0 + 8 * e;
      if (i != j) { float a = A[i][j]; off2 += a * a; }
    }
#pragma unroll
    for (int o = 32; o; o >>= 1) off2 += __shfl_xor(off2, o, 64);
    if ((tid & 63) == 0) wred[tid >> 6] = off2;
    __syncthreads();
    if (tid == 0) done = ((wred[0] + wred[1] + wred[2] + wred[3]) < tolS) ? 1 : 0;
    __syncthreads();
    if (done) break;
  }

  if (tid < 32) { lam[tid] = A[tid][tid]; ord[tid] = tid; }
  __syncthreads();
  if (tid == 0) {
    for (int a = 0; a < 31; a++) {
      int mi = a;
      for (int b3 = a + 1; b3 < 32; b3++) if (lam[b3] > lam[mi]) mi = b3;
      float tl = lam[a]; lam[a] = lam[mi]; lam[mi] = tl;
      int to = ord[a]; ord[a] = ord[mi]; ord[mi] = to;
    }
    float tot = 0.f;
    for (int a = 0; a < 32; a++) tot += lam[a];
    float cum = 0.f; int P = 0;
    for (int a = 0; a < 32; a++) { float rate = lam[a] / tot; if (cum < 0.8f) P++; cum += rate; }
    Psh = P;
  }
  __syncthreads();
#pragma unroll
  for (int e = 0; e < 4; e++) {
    int i = i0 + 8 * e;
    Y[i][j] = (j < Psh) ? V[i][ord[j]] * sqrtf(fmaxf(lam[j], 0.f)) : 0.f;
  }
  __syncthreads();
  { int jj = tid >> 5, kk = tid & 31; C[jj][kk] = Y[jj][kk]; }
  __syncthreads();

  for (int it = 0; it <= 20; it++) {
    {
      int ii = tid >> 3, jj = tid & 7;
      float s = 0.f;
      for (int kk = 0; kk < 32; kk++) { float d = Y[ii][kk] - C[jj][kk]; s += d * d; }
      D[ii][jj] = s;
    }
    __syncthreads();
    if (tid < 32) {
      int best = 0; float bd = D[tid][0];
      for (int jj = 1; jj < 8; jj++) if (D[tid][jj] < bd) { bd = D[tid][jj]; best = jj; }
      asg[tid] = best;
    }
    __syncthreads();
    if (it == 20) break;
    if (tid < 8) { int s = 0; for (int ii = 0; ii < 32; ii++) s += (asg[ii] == tid); cnt[tid] = s; }
    __syncthreads();
    {
      int jj = tid >> 5, kk = tid & 31;
      if (cnt[jj] > 0) {
        float s = 0.f;
        for (int ii = 0; ii < 32; ii++) if (asg[ii] == jj) s += Y[ii][kk];
        C[jj][kk] = s / (float)cnt[jj];
      }
    }
    __syncthreads();
  }
  if (tid < 32) r[tid] = asg[tid];
}

// ---------------- conversion kernels ----------------

// f32 [E][K][N] -> bf16 [E][N][K] (transpose per expert)
__global__ __launch_bounds__(256) void wcvt(const float* __restrict__ in, unsigned short* __restrict__ out,
                                            int K, int N) {
  __shared__ float T[64][65];
  int e = blockIdx.z;
  int tid = threadIdx.x;
  int tr = tid >> 4, tc = tid & 15;
  const float* ip = in + (size_t)e * K * N + (size_t)(blockIdx.y * 64) * N + blockIdx.x * 64;
  unsigned short* op = out + (size_t)e * N * K + (size_t)(blockIdx.x * 64) * K + blockIdx.y * 64;
#pragma unroll
  for (int rep = 0; rep < 4; rep++) {
    int row = rep * 16 + tr;
    float4 v = *(const float4*)(ip + (size_t)row * N + tc * 4);
    T[row][tc * 4 + 0] = v.x; T[row][tc * 4 + 1] = v.y;
    T[row][tc * 4 + 2] = v.z; T[row][tc * 4 + 3] = v.w;
  }
  __syncthreads();
#pragma unroll
  for (int rep = 0; rep < 4; rep++) {
    int nrow = rep * 16 + tr;
    float a = T[tc * 4 + 0][nrow], b = T[tc * 4 + 1][nrow];
    float c = T[tc * 4 + 2][nrow], d = T[tc * 4 + 3][nrow];
    uint2 wv; wv.x = packpair(a, b); wv.y = packpair(c, d);
    *(uint2*)(op + (size_t)nrow * K + tc * 4) = wv;
  }
}

__global__ __launch_bounds__(256) void xcvt(const float* __restrict__ in, unsigned short* __restrict__ out, int n8) {
  int idx = blockIdx.x * 256 + threadIdx.x;
  if (idx >= n8) return;
  const float* p = in + (size_t)idx * 8;
  float t[8];
  float4 a = *(const float4*)p, b = *(const float4*)(p + 4);
  t[0] = a.x; t[1] = a.y; t[2] = a.z; t[3] = a.w;
  t[4] = b.x; t[5] = b.y; t[6] = b.z; t[7] = b.w;
  *(short8*)(out + (size_t)idx * 8) = pack8(t);
}

// ---------------- bf16 MFMA expert GEMM (m97 structure) ----------------
// A bf16 [nbatch][512][lda]; Bt bf16 [E][N][K]; Y bf16 [nbatch][512][N].
// RES: 0 none, 1 f32 residual, 2 bf16 residual.
template <int ACT, int RES>
__global__ __launch_bounds__(256) void gemm_bt(
    const unsigned short* __restrict__ A, const unsigned short* __restrict__ Bt,
    const float* __restrict__ bias, const void* __restrict__ res,
    unsigned short* __restrict__ Y, const int* __restrict__ r,
    int K, int N, int lda, int bofs) {
  __shared__ __align__(16) unsigned short As[4096];  // 128 rows x 32 k
  __shared__ __align__(16) unsigned short Bs[4096];  // 128 cols x 32 k
  int z = blockIdx.z;
  int e = r[bofs + z];
  int tid = threadIdx.x;
  int wid = tid >> 6, lane = tid & 63;
  int wy = wid >> 1, wx = wid & 1;
  int lr = lane & 15, lg = lane >> 4;
  const unsigned short* Ab = A + (size_t)z * Sn * lda + (size_t)blockIdx.y * 128 * lda;
  const unsigned short* Bb = Bt + (size_t)e * N * K + (size_t)blockIdx.x * 128 * K;
  int r0 = wid * 16 + (lane >> 2);
  int r1 = (4 + wid) * 16 + (lane >> 2);
  int kk = (lane & 3) * 8;
  unsigned short* As0 = As + (size_t)wid * 512;
  unsigned short* As1 = As + (size_t)(4 + wid) * 512;
  unsigned short* Bs0 = Bs + (size_t)wid * 512;
  unsigned short* Bs1 = Bs + (size_t)(4 + wid) * 512;

  f32x4 acc[4][4];
#pragma unroll
  for (int m = 0; m < 4; m++)
#pragma unroll
    for (int n = 0; n < 4; n++) acc[m][n] = (f32x4){0.f, 0.f, 0.f, 0.f};

  for (int k0 = 0; k0 < K; k0 += 32) {
    gload16(Ab + (size_t)r0 * lda + k0 + kk, As0);
    gload16(Ab + (size_t)r1 * lda + k0 + kk, As1);
    gload16(Bb + (size_t)r0 * K + k0 + kk, Bs0);
    gload16(Bb + (size_t)r1 * K + k0 + kk, Bs1);
    __syncthreads();
    short8 af[4], bf[4];
#pragma unroll
    for (int m = 0; m < 4; m++) af[m] = *(const short8*)&As[(wy * 64 + m * 16 + lr) * 32 + lg * 8];
#pragma unroll
    for (int n = 0; n < 4; n++) bf[n] = *(const short8*)&Bs[(wx * 64 + n * 16 + lr) * 32 + lg * 8];
#pragma unroll
    for (int m = 0; m < 4; m++)
#pragma unroll
      for (int n = 0; n < 4; n++)
        acc[m][n] = __builtin_amdgcn_mfma_f32_16x16x32_bf16(af[m], bf[n], acc[m][n], 0, 0, 0);
    __syncthreads();
  }

  int row0 = blockIdx.y * 128 + wy * 64;
  int col0 = blockIdx.x * 128 + wx * 64;
#pragma unroll
  for (int m = 0; m < 4; m++) {
#pragma unroll
    for (int n = 0; n < 4; n++) {
      int col = col0 + n * 16 + lr;
      float bias_v = bias[e * N + col];
#pragma unroll
      for (int rr = 0; rr < 4; rr++) {
        int row = row0 + m * 16 + lg * 4 + rr;
        size_t off = ((size_t)z * Sn + row) * N + col;
        float v = acc[m][n][rr] + bias_v;
        if (RES == 1) v += ((const float*)res)[off];
        if (RES == 2) v += b2f(((const unsigned short*)res)[off]);
        if (ACT == 1) v = fast_gelu(v);
        Y[off] = f2b(v);
      }
    }
  }
}

// ---------------- MFMA flash attention (bf16 in/out) ----------------
__global__ __launch_bounds__(256) void attn_mfma(
    const unsigned short* qb, const unsigned short* __restrict__ kb,
    const unsigned short* __restrict__ vb, const float* __restrict__ amask,
    unsigned short* ctx) {
  __shared__ short Kl[32][72];
  __shared__ short Vt[64][40];
  __shared__ float mk[512];
  int qt = blockIdx.x, h = blockIdx.y, b = blockIdx.z;
  int tid = threadIdx.x, w = tid >> 6, lane = tid & 63;
  int lr = lane & 15, lg = lane >> 4;

  for (int i2 = tid; i2 < 512; i2 += 256) mk[i2] = (1.f - amask[b * Sn + i2]) * (-10000.f);

  int qrow = qt * 64 + w * 16 + lr;
  const unsigned short* qp = qb + ((size_t)(b * Sn + qrow)) * Hn + h * 64 + lg * 8;
  short8 qf0 = *(const short8*)qp;
  short8 qf1 = *(const short8*)(qp + 32);

  f32x4 o[4];
#pragma unroll
  for (int f = 0; f < 4; f++) o[f] = (f32x4){0.f, 0.f, 0.f, 0.f};
  float mrun = -3e38f, lsum = 0.f;

  for (int kv0 = 0; kv0 < Sn; kv0 += 32) {
    __syncthreads();
    {  // K tile [32][64] bf16
      int kvr = tid >> 3, i8 = tid & 7;
      const unsigned short* kp = kb + ((size_t)(b * Sn + kv0 + kvr)) * Hn + h * 64 + i8 * 8;
      *(short8*)&Kl[kvr][i8 * 8] = *(const short8*)kp;
    }
    {  // V^T tile [64 d][32 kv]
      int d = tid & 63, kq = tid >> 6;
      const unsigned short* vp = vb + ((size_t)(b * Sn + kv0 + kq * 8)) * Hn + h * 64 + d;
      unsigned a0 = (unsigned)vp[0] | ((unsigned)vp[Hn] << 16);
      unsigned a1 = (unsigned)vp[2 * Hn] | ((unsigned)vp[3 * Hn] << 16);
      unsigned a2 = (unsigned)vp[4 * Hn] | ((unsigned)vp[5 * Hn] << 16);
      unsigned a3 = (unsigned)vp[6 * Hn] | ((unsigned)vp[7 * Hn] << 16);
      int4v wv; wv.x = (int)a0; wv.y = (int)a1; wv.z = (int)a2; wv.w = (int)a3;
      *(short8*)&Vt[d][kq * 8] = __builtin_bit_cast(short8, wv);
    }
    __syncthreads();

    f32x4 s0 = (f32x4){0.f, 0.f, 0.f, 0.f}, s1 = s0;
    short8 k00 = *(short8*)&Kl[lr][lg * 8];
    short8 k01 = *(short8*)&Kl[lr][32 + lg * 8];
    short8 k10 = *(short8*)&Kl[16 + lr][lg * 8];
    short8 k11 = *(short8*)&Kl[16 + lr][32 + lg * 8];
    s0 = __builtin_amdgcn_mfma_f32_16x16x32_bf16(k00, qf0, s0, 0, 0, 0);
    s0 = __builtin_amdgcn_mfma_f32_16x16x32_bf16(k01, qf1, s0, 0, 0, 0);
    s1 = __builtin_amdgcn_mfma_f32_16x16x32_bf16(k10, qf0, s1, 0, 0, 0);
    s1 = __builtin_amdgcn_mfma_f32_16x16x32_bf16(k11, qf1, s1, 0, 0, 0);

    f32x4 m0 = *(f32x4*)&mk[kv0 + lg * 4];
    f32x4 m1 = *(f32x4*)&mk[kv0 + 16 + lg * 4];
#pragma unroll
    for (int rr = 0; rr < 4; rr++) { s0[rr] = s0[rr] * 0.125f + m0[rr]; s1[rr] = s1[rr] * 0.125f + m1[rr]; }

    float pm = fmaxf(fmaxf(fmaxf(s0[0], s0[1]), fmaxf(s0[2], s0[3])),
                     fmaxf(fmaxf(s1[0], s1[1]), fmaxf(s1[2], s1[3])));
    pm = fmaxf(pm, __shfl_xor(pm, 16, 64));
    pm = fmaxf(pm, __shfl_xor(pm, 32, 64));
    float mn = fmaxf(mrun, pm);
    float al = __expf(mrun - mn);
    float p0[4], p1[4];
    float ls = 0.f;
#pragma unroll
    for (int rr = 0; rr < 4; rr++) { p0[rr] = __expf(s0[rr] - mn); ls += p0[rr]; }
#pragma unroll
    for (int rr = 0; rr < 4; rr++) { p1[rr] = __expf(s1[rr] - mn); ls += p1[rr]; }
    ls += __shfl_xor(ls, 16, 64);
    ls += __shfl_xor(ls, 32, 64);
    lsum = lsum * al + ls;
    mrun = mn;
#pragma unroll
    for (int f = 0; f < 4; f++)
#pragma unroll
      for (int rr = 0; rr < 4; rr++) o[f][rr] *= al;

    unsigned a0p = packpair(p0[0], p0[1]), a1p = packpair(p0[2], p0[3]);
    unsigned b0p = packpair(p1[0], p1[1]), b1p = packpair(p1[2], p1[3]);
    int srcA = lr + (((2 * lg) & 3) << 4);
    int srcB = srcA + 16;
    unsigned xa0 = __shfl(a0p, srcA, 64), xa1 = __shfl(a1p, srcA, 64);
    unsigned xb0 = __shfl(b0p, srcA, 64), xb1 = __shfl(b1p, srcA, 64);
    unsigned ya0 = __shfl(a0p, srcB, 64), ya1 = __shfl(a1p, srcB, 64);
    unsigned yb0 = __shfl(b0p, srcB, 64), yb1 = __shfl(b1p, srcB, 64);
    bool lo = lg < 2;
    int4v pw;
    pw.x = (int)(lo ? xa0 : xb0); pw.y = (int)(lo ? xa1 : xb1);
    pw.z = (int)(lo ? ya0 : yb0); pw.w = (int)(lo ? ya1 : yb1);
    short8 pf = __builtin_bit_cast(short8, pw);

#pragma unroll
    for (int f = 0; f < 4; f++) {
      short8 vf = *(short8*)&Vt[f * 16 + lr][lg * 8];
      o[f] = __builtin_amdgcn_mfma_f32_16x16x32_bf16(vf, pf, o[f], 0, 0, 0);
    }
  }

  float inv = 1.f / lsum;
  unsigned short* op = ctx + ((size_t)(b * Sn + qt * 64 + w * 16 + lr)) * Hn + h * 64;
#pragma unroll
  for (int f = 0; f < 4; f++) {
    uint2 wv;
    wv.x = packpair(o[f][0] * inv, o[f][1] * inv);
    wv.y = packpair(o[f][2] * inv, o[f][3] * inv);
    *(uint2*)(op + f * 16 + lg * 4) = wv;
  }
}

// ---------------- layernorm (bf16 in; bf16 or f32 out) ----------------
template <int OUTF32>
__global__ __launch_bounds__(256) void ln_bf(const unsigned short* __restrict__ X, void* __restrict__ Yv,
    const float* __restrict__ gam, const float* __restrict__ bet, const int* __restrict__ r) {
  __shared__ float red1[4], red2[4];
  int row = blockIdx.x;
  int tid = threadIdx.x;
  const unsigned short* x = X + (size_t)row * Hn;
  float v0 = b2f(x[tid]), v1 = b2f(x[tid + 256]), v2 = b2f(x[tid + 512]);
  float s = v0 + v1 + v2;
#pragma unroll
  for (int o = 32; o; o >>= 1) s += __shfl_xor(s, o, 64);
  if ((tid & 63) == 0) red1[tid >> 6] = s;
  __syncthreads();
  float mu = (red1[0] + red1[1] + red1[2] + red1[3]) * (1.f / (float)Hn);
  float d0 = v0 - mu, d1 = v1 - mu, d2 = v2 - mu;
  float q = d0 * d0 + d1 * d1 + d2 * d2;
#pragma unroll
  for (int o = 32; o; o >>= 1) q += __shfl_xor(q, o, 64);
  if ((tid & 63) == 0) red2[tid >> 6] = q;
  __syncthreads();
  float var = (red2[0] + red2[1] + red2[2] + red2[3]) * (1.f / (float)Hn);
  float inv = rsqrtf(var + 1e-12f);
  int e = r[row >> 9];
  const float* g = gam + e * Hn;
  const float* be = bet + e * Hn;
  float o0 = d0 * inv * g[tid] + be[tid];
  float o1 = d1 * inv * g[tid + 256] + be[tid + 256];
  float o2 = d2 * inv * g[tid + 512] + be[tid + 512];
  if (OUTF32) {
    float* y = (float*)Yv + (size_t)row * Hn;
    y[tid] = o0; y[tid + 256] = o1; y[tid + 512] = o2;
  } else {
    unsigned short* y = (unsigned short*)Yv + (size_t)row * Hn;
    y[tid] = f2b(o0); y[tid + 256] = f2b(o1); y[tid + 512] = f2b(o2);
  }
}

// ---------------- launch ----------------
extern "C" void kernel_launch(void* const* d_in, const int* in_sizes, int n_in,
                              void* d_out, int out_size, void* d_ws, size_t ws_size,
                              hipStream_t stream) {
  const float* hidden = (const float*)d_in[0];
  const float* amask  = (const float*)d_in[1];
  const float* Wq = (const float*)d_in[2];
  const float* bq = (const float*)d_in[3];
  const float* Wk = (const float*)d_in[4];
  const float* bk = (const float*)d_in[5];
  const float* Wv = (const float*)d_in[6];
  const float* bv = (const float*)d_in[7];
  const float* Wo = (const float*)d_in[8];
  const float* bo = (const float*)d_in[9];
  const float* g1 = (const float*)d_in[10];
  const float* b1g = (const float*)d_in[11];
  const float* W1 = (const float*)d_in[12];
  const float* b1 = (const float*)d_in[13];
  const float* W2 = (const float*)d_in[14];
  const float* b2 = (const float*)d_in[15];
  const float* g2 = (const float*)d_in[16];
  const float* b2g = (const float*)d_in[17];
  float* out = (float*)d_out;

  char* w = (char*)d_ws;
  int* r = (int*)w;                              // 128 B
  float* gA = (float*)(w + 1024);                // 4 KB
  float* cbuf = (float*)(w + 8192);              // 96 KB
  const size_t TOK = (size_t)Bn * Sn;            // 16384
  size_t off = (size_t)1 << 20;
  const size_t WSML = (size_t)En * Hn * Hn * 2;        // 9.4 MB
  const size_t WBIG = (size_t)En * Hn * INTERn * 2;    // 37.7 MB
  const size_t ABUF = TOK * Hn * 2;                    // 25.2 MB (== 8*512*3072*2)
  unsigned short* Wqt = (unsigned short*)(w + off); off += WSML;
  unsigned short* Wkt = (unsigned short*)(w + off); off += WSML;
  unsigned short* Wvt = (unsigned short*)(w + off); off += WSML;
  unsigned short* Wot = (unsigned short*)(w + off); off += WSML;
  unsigned short* W1t = (unsigned short*)(w + off); off += WBIG;
  unsigned short* W2t = (unsigned short*)(w + off); off += WBIG;
  unsigned short* xb  = (unsigned short*)(w + off); off += ABUF;  // x_bf -> att_bf
  unsigned short* qb2 = (unsigned short*)(w + off); off += ABUF;  // q -> ctx
  unsigned short* kb2 = (unsigned short*)(w + off); off += ABUF;  // k -> ffn_pre
  unsigned short* vb2 = (unsigned short*)(w + off); off += ABUF;  // v
  unsigned short* pb  = (unsigned short*)(w + off); off += ABUF;  // att_pre -> h1 chunk
  // total ~229 MB

  // routing
  sent_kernel<<<dim3(32, 3), 256, 0, stream>>>(hidden, cbuf);
  center_kernel<<<3, 256, 0, stream>>>(cbuf);
  gram_kernel<<<1, 1024, 0, stream>>>(cbuf, gA);
  route_kernel<<<1, 256, 0, stream>>>(gA, r);

  // bf16 conversions (r-independent)
  wcvt<<<dim3(12, 12, 8), 256, 0, stream>>>(Wq, Wqt, Hn, Hn);
  wcvt<<<dim3(12, 12, 8), 256, 0, stream>>>(Wk, Wkt, Hn, Hn);
  wcvt<<<dim3(12, 12, 8), 256, 0, stream>>>(Wv, Wvt, Hn, Hn);
  wcvt<<<dim3(12, 12, 8), 256, 0, stream>>>(Wo, Wot, Hn, Hn);
  wcvt<<<dim3(48, 12, 8), 256, 0, stream>>>(W1, W1t, Hn, INTERn);
  wcvt<<<dim3(12, 48, 8), 256, 0, stream>>>(W2, W2t, INTERn, Hn);
  xcvt<<<6144, 256, 0, stream>>>(hidden, xb, (int)(TOK * Hn / 8));

  // q, k, v projections
  gemm_bt<0, 0><<<dim3(6, 4, 32), 256, 0, stream>>>(xb, Wqt, bq, nullptr, qb2, r, Hn, Hn, Hn, 0);
  gemm_bt<0, 0><<<dim3(6, 4, 32), 256, 0, stream>>>(xb, Wkt, bk, nullptr, kb2, r, Hn, Hn, Hn, 0);
  gemm_bt<0, 0><<<dim3(6, 4, 32), 256, 0, stream>>>(xb, Wvt, bv, nullptr, vb2, r, Hn, Hn, Hn, 0);

  // attention (ctx in-place over qb2)
  attn_mfma<<<dim3(8, 12, 32), 256, 0, stream>>>(qb2, kb2, vb2, amask, qb2);

  // output projection + f32 residual(hidden) -> pb (att_pre bf16); LN1 -> xb (att_bf)
  gemm_bt<0, 1><<<dim3(6, 4, 32), 256, 0, stream>>>(qb2, Wot, bo, hidden, pb, r, Hn, Hn, Hn, 0);
  ln_bf<0><<<16384, 256, 0, stream>>>(pb, xb, g1, b1g, r);

  // FFN chunked (G=8): h1 chunk in pb; ffn_pre -> kb2
  const int G = 8;
  for (int c = 0; c < Bn / G; c++) {
    const unsigned short* attc = xb + (size_t)c * G * Sn * Hn;
    unsigned short* ffc = kb2 + (size_t)c * G * Sn * Hn;
    gemm_bt<1, 0><<<dim3(24, 4, G), 256, 0, stream>>>(attc, W1t, b1, nullptr, pb, r, Hn, INTERn, Hn, c * G);
    gemm_bt<0, 2><<<dim3(6, 4, G), 256, 0, stream>>>(pb, W2t, b2, attc, ffc, r, INTERn, Hn, INTERn, c * G);
  }
  ln_bf<1><<<16384, 256, 0, stream>>>(kb2, out, g2, b2g, r);
}